// Round 20
// baseline (164.727 us; speedup 1.0000x reference)
//
#include <hip/hip_runtime.h>

#define BDIM 256
#define KC_STRIDE 28                  // per (case,co): K[0..24], bias at [25], 2 pad
#define CASE_STRIDE (32 * KC_STRIDE)  // 896 floats per border-case
#define SP 1032                       // S plane stride (16 rows x 64 + 8 pad)

// ws float offsets (after the 25 collapsed-case kernels)
#define OFF_M 22400    // M[9 tap][9 e][32 co]
#define OFF_MR 24992   // MR[3 di][15 = ei*5+v][32]
#define OFF_MC 26432   // MC[3 dj][15 = u*3+ej][32]
#define OFF_BVR 27872  // BvR[3][32]
#define OFF_BVC 27968  // BvC[3][32]
#define OFF_BV 28064   // Bv[9][32]

typedef float floatx4 __attribute__((ext_vector_type(4)));

__device__ __forceinline__ int casef(int p) {
  return ((unsigned)(p - 2) < 60u) ? 2 : (p < 2 ? p : p - 59);
}

// ---------------- prep: collapsed kernels + correction tables ----------------
__global__ __launch_bounds__(BDIM) void prep_kernel(
    const float* __restrict__ W1, const float* __restrict__ b1,
    const float* __restrict__ W2, const float* __restrict__ b2,
    float* __restrict__ ws) {
  __shared__ float Mlds[9 * 9 * 32];
  __shared__ float BvL[9 * 32];
  const int tid = threadIdx.x;
  const int co = tid & 31;
  for (int tap = tid >> 5; tap < 9; tap += 8) {
    float acc[9] = {0.f, 0.f, 0.f, 0.f, 0.f, 0.f, 0.f, 0.f, 0.f};
    float accB = 0.f;
    for (int ci = 0; ci < 64; ++ci) {
      float w2 = W2[(tap * 64 + ci) * 32 + co];
      accB = fmaf(b1[ci], w2, accB);
#pragma unroll
      for (int e = 0; e < 9; ++e) acc[e] = fmaf(W1[e * 64 + ci], w2, acc[e]);
    }
#pragma unroll
    for (int e = 0; e < 9; ++e) Mlds[(tap * 9 + e) * 32 + co] = acc[e];
    BvL[tap * 32 + co] = accB;
  }
  __syncthreads();

  if (blockIdx.x < 25) {
    const int a = blockIdx.x / 5, c = blockIdx.x % 5;
    const int dmask[5] = {4, 6, 7, 3, 1};
    const int Da = dmask[a], Dc = dmask[c];
    for (int t = tid; t < CASE_STRIDE; t += BDIM) {
      int cc = t / KC_STRIDE, r = t % KC_STRIDE;
      float s = 0.f;
      if (r < 25) {
        int u = r / 5, v = r % 5;
        for (int di = 0; di < 3; ++di) {
          if (!((Da >> di) & 1)) continue;
          int ei = u - di;
          if ((unsigned)ei > 2u) continue;
          for (int dj = 0; dj < 3; ++dj) {
            if (!((Dc >> dj) & 1)) continue;
            int ej = v - dj;
            if ((unsigned)ej > 2u) continue;
            s += Mlds[((di * 3 + dj) * 9 + ei * 3 + ej) * 32 + cc];
          }
        }
      } else if (r == 25) {
        s = b2[cc];
        for (int di = 0; di < 3; ++di)
          if ((Da >> di) & 1)
            for (int dj = 0; dj < 3; ++dj)
              if ((Dc >> dj) & 1) s += BvL[(di * 3 + dj) * 32 + cc];
      }
      ws[blockIdx.x * CASE_STRIDE + t] = s;
    }
  } else {
    // block 25: correction tables
    for (int t = tid; t < 2592; t += BDIM) ws[OFF_M + t] = Mlds[t];
    for (int t = tid; t < 1440; t += BDIM) {
      int di = t / 480, r = (t / 32) % 15, cc = t & 31;
      int ei = r / 5, v = r % 5;
      float s = 0.f;
      for (int dj = 0; dj < 3; ++dj) {
        int ej = v - dj;
        if ((unsigned)ej <= 2u) s += Mlds[((di * 3 + dj) * 9 + ei * 3 + ej) * 32 + cc];
      }
      ws[OFF_MR + t] = s;
    }
    for (int t = tid; t < 1440; t += BDIM) {
      int dj = t / 480, r = (t / 32) % 15, cc = t & 31;
      int u = r / 3, ej = r % 3;
      float s = 0.f;
      for (int di = 0; di < 3; ++di) {
        int ei = u - di;
        if ((unsigned)ei <= 2u) s += Mlds[((di * 3 + dj) * 9 + ei * 3 + ej) * 32 + cc];
      }
      ws[OFF_MC + t] = s;
    }
    for (int t = tid; t < 96; t += BDIM) {
      int di = t >> 5, cc = t & 31;
      float s = 0.f;
      for (int dj = 0; dj < 3; ++dj) s += BvL[(di * 3 + dj) * 32 + cc];
      ws[OFF_BVR + t] = s;
    }
    for (int t = tid; t < 96; t += BDIM) {
      int dj = t >> 5, cc = t & 31;
      float s = 0.f;
      for (int di = 0; di < 3; ++di) s += BvL[(di * 3 + dj) * 32 + cc];
      ws[OFF_BVC + t] = s;
    }
    for (int t = tid; t < 288; t += BDIM) ws[OFF_BV + t] = BvL[t];
  }
}

// corrections: all indices compile-time (rule #20: no runtime reg-array idx)
#define ROWCORR(DI)                                                            \
  { float bv = BvRl[(DI)*32 + co]; z0 -= bv; z1 -= bv; z2 -= bv; z3 -= bv;     \
    _Pragma("unroll") for (int ei = 0; ei < 3; ++ei)                           \
    _Pragma("unroll") for (int v = 0; v < 5; ++v) {                            \
      float m = MRl[((DI)*15 + ei*5 + v)*32 + co];                             \
      z0 = fmaf(-xw[(DI)+ei][v], m, z0);   z1 = fmaf(-xw[(DI)+ei][v+1], m, z1);\
      z2 = fmaf(-xw[(DI)+ei][v+2], m, z2); z3 = fmaf(-xw[(DI)+ei][v+3], m, z3);} }

#define COLCORR(DJ, J, Z)                                                      \
  { Z -= BvCl[(DJ)*32 + co];                                                   \
    _Pragma("unroll") for (int u = 0; u < 5; ++u)                              \
    _Pragma("unroll") for (int ej = 0; ej < 3; ++ej)                           \
      Z = fmaf(-xw[u][(DJ)+ej+(J)], MCl[((DJ)*15 + u*3 + ej)*32 + co], Z); }

#define CORNER(DI, DJ, J, Z)                                                   \
  { Z += Bvl[((DI)*3+(DJ))*32 + co];                                           \
    _Pragma("unroll") for (int ei = 0; ei < 3; ++ei)                           \
    _Pragma("unroll") for (int ej = 0; ej < 3; ++ej)                           \
      Z = fmaf(xw[(DI)+ei][(DJ)+ej+(J)],                                       \
               Ml[(((DI)*3+(DJ))*9 + ei*3 + ej)*32 + co], Z); }

// ---- main: R17 structure; border via in-LDS corrections (NO in-loop vmem) ----
__global__ __launch_bounds__(BDIM) void main_kernel(
    const float* __restrict__ x, const float* __restrict__ ws,
    float* __restrict__ out) {
  const int bb = blockIdx.x;
  const int b = bb >> 1;
  const int r0 = (bb & 1) << 5;  // 0 or 32
  const int tid = threadIdx.x;
  const int lane = tid & 63;
  const int wave = tid >> 6;

  __shared__ __align__(16) float xp[36 * 68];
  __shared__ __align__(16) float S[8][SP];
  __shared__ __align__(16) float KiL[CASE_STRIDE];
  __shared__ float Ml[2592], MRl[1440], MCl[1440];
  __shared__ float BvRl[96], BvCl[96], Bvl[288];
  __shared__ unsigned long long Rm[32];
  __shared__ unsigned short aqi[2][224], aqb[2][64];
  __shared__ int nqi_sh[2], nqb_sh[2];

  if (tid < 2) { nqi_sh[tid] = 0; nqb_sh[tid] = 0; }
  float4* xp4 = reinterpret_cast<float4*>(xp);
  for (int i = tid; i < 612; i += BDIM) xp4[i] = make_float4(0.f, 0.f, 0.f, 0.f);
  for (int i = tid; i < CASE_STRIDE; i += BDIM) KiL[i] = ws[12 * CASE_STRIDE + i];
  for (int i = tid; i < 2592; i += BDIM) Ml[i] = ws[OFF_M + i];
  for (int i = tid; i < 1440; i += BDIM) { MRl[i] = ws[OFF_MR + i]; MCl[i] = ws[OFF_MC + i]; }
  if (tid < 96) { BvRl[tid] = ws[OFF_BVR + tid]; BvCl[tid] = ws[OFF_BVC + tid]; }
  for (int i = tid; i < 288; i += BDIM) Bvl[i] = ws[OFF_BV + i];
  __syncthreads();

  const float* xb = x + (size_t)b * 4096;
  for (int it = tid; it < 576; it += BDIM) {
    int i = it >> 4, c4 = (it & 15) << 2;
    int r = r0 - 2 + i;
    if ((unsigned)r < 64u) {
      float4 v = *reinterpret_cast<const float4*>(xb + r * 64 + c4);
      float2* d2 = reinterpret_cast<float2*>(&xp[i * 68 + 2 + c4]);
      d2[0] = make_float2(v.x, v.y);
      d2[1] = make_float2(v.z, v.w);
    }
  }
  __syncthreads();

  for (int k = wave; k < 32; k += 4) {
    int pred = (xp[(k + 2) * 68 + 2 + lane] != 0.0f);
    unsigned long long m = __ballot(pred);
    if (lane == 0) Rm[k] = m;
  }
  __syncthreads();

  for (int g = tid; g < 512; g += BDIM) {
    int k = g >> 4, q0 = (g & 15) << 2;
    unsigned bits = (unsigned)(Rm[k] >> q0) & 0xFu;
    if (!bits) continue;
    int h = k >> 4;
    int p = r0 + k;
    bool inter = ((unsigned)(p - 2) < 60u) && ((unsigned)(q0 - 4) <= 52u);
    if (inter) {
      aqi[h][atomicAdd(&nqi_sh[h], 1)] = (unsigned short)g;
    } else {
      aqb[h][atomicAdd(&nqb_sh[h], 1)] = (unsigned short)g;
    }
  }
  __syncthreads();

  const int ni0 = nqi_sh[0], ni1 = nqi_sh[1];
  const int nb0 = nqb_sh[0], nb1 = nqb_sh[1];
  float* outb = out + (size_t)b * (32 * 4096);

  // 8 substages: t -> (channel octet cg = t>>1, row half h = t&1)
  for (int t = 0; t < 8; ++t) {
    const int cg = t >> 1, h = t & 1;
    const int ni = h ? ni1 : ni0;
    const int nb = h ? nb1 : nb0;
    // ---- interior quads: co-paired (2 ch per window read) ----
    for (int n = tid; n < ni * 4; n += BDIM) {
      int g = aqi[h][n >> 2];
      int co4 = n & 3;
      int co_lo = (cg << 3) + co4;
      int k = g >> 4, q0 = (g & 15) << 2;
      const float* Ka = &KiL[co_lo * KC_STRIDE];
      const float* Kb = &KiL[(co_lo + 4) * KC_STRIDE];
      float ba = Ka[25], bbv = Kb[25];
      float a0 = ba, a1 = ba, a2 = ba, a3 = ba;
      float b0 = bbv, b1 = bbv, b2 = bbv, b3 = bbv;
#pragma unroll
      for (int u = 0; u < 5; ++u) {
        const float* xr = &xp[(k + u) * 68 + q0];
        float4 xa = *reinterpret_cast<const float4*>(xr);
        float4 xc = *reinterpret_cast<const float4*>(xr + 4);
        float xv[8] = {xa.x, xa.y, xa.z, xa.w, xc.x, xc.y, xc.z, xc.w};
#pragma unroll
        for (int v = 0; v < 5; ++v) {
          float ka = Ka[u * 5 + v], kb = Kb[u * 5 + v];
          a0 = fmaf(xv[v], ka, a0);
          a1 = fmaf(xv[v + 1], ka, a1);
          a2 = fmaf(xv[v + 2], ka, a2);
          a3 = fmaf(xv[v + 3], ka, a3);
          b0 = fmaf(xv[v], kb, b0);
          b1 = fmaf(xv[v + 1], kb, b1);
          b2 = fmaf(xv[v + 2], kb, b2);
          b3 = fmaf(xv[v + 3], kb, b3);
        }
      }
      int so = ((k & 15) << 6) + q0;
      *reinterpret_cast<float4*>(&S[co4][so]) = make_float4(a0, a1, a2, a3);
      *reinterpret_cast<float4*>(&S[co4 + 4][so]) = make_float4(b0, b1, b2, b3);
    }
    // ---- border quads: interior kernel + inclusion-exclusion corrections ----
    for (int n = tid; n < nb * 8; n += BDIM) {
      int g = aqb[h][n >> 3];
      int cs = n & 7;  // lane-static
      int co = (cg << 3) + cs;
      int k = g >> 4, q0 = (g & 15) << 2;
      int p = r0 + k;
      float xw[5][8];
#pragma unroll
      for (int u = 0; u < 5; ++u) {
        const float* xr = &xp[(k + u) * 68 + q0];
        float4 xa = *reinterpret_cast<const float4*>(xr);
        float4 xc = *reinterpret_cast<const float4*>(xr + 4);
        xw[u][0] = xa.x; xw[u][1] = xa.y; xw[u][2] = xa.z; xw[u][3] = xa.w;
        xw[u][4] = xc.x; xw[u][5] = xc.y; xw[u][6] = xc.z; xw[u][7] = xc.w;
      }
      const float* Ki = &KiL[co * KC_STRIDE];
      float bias = Ki[25];
      float z0 = bias, z1 = bias, z2 = bias, z3 = bias;
#pragma unroll
      for (int u = 0; u < 5; ++u) {
#pragma unroll
        for (int v = 0; v < 5; ++v) {
          float kv = Ki[u * 5 + v];
          z0 = fmaf(xw[u][v], kv, z0);
          z1 = fmaf(xw[u][v + 1], kv, z1);
          z2 = fmaf(xw[u][v + 2], kv, z2);
          z3 = fmaf(xw[u][v + 3], kv, z3);
        }
      }
      // row corrections (inv di sets: p=0:{0,1} 1:{0} 62:{2} 63:{1,2})
      if (p == 0)       { ROWCORR(0) ROWCORR(1) }
      else if (p == 1)  { ROWCORR(0) }
      else if (p == 62) { ROWCORR(2) }
      else if (p == 63) { ROWCORR(1) ROWCORR(2) }
      // col corrections + corner add-backs (only q0==0 or q0==60 have any)
      if (q0 == 0) {
        COLCORR(0, 0, z0) COLCORR(1, 0, z0) COLCORR(0, 1, z1)
        if (p == 0)       { CORNER(0,0,0,z0) CORNER(0,1,0,z0) CORNER(0,0,1,z1)
                            CORNER(1,0,0,z0) CORNER(1,1,0,z0) CORNER(1,0,1,z1) }
        else if (p == 1)  { CORNER(0,0,0,z0) CORNER(0,1,0,z0) CORNER(0,0,1,z1) }
        else if (p == 62) { CORNER(2,0,0,z0) CORNER(2,1,0,z0) CORNER(2,0,1,z1) }
        else if (p == 63) { CORNER(1,0,0,z0) CORNER(1,1,0,z0) CORNER(1,0,1,z1)
                            CORNER(2,0,0,z0) CORNER(2,1,0,z0) CORNER(2,0,1,z1) }
      } else if (q0 == 60) {
        COLCORR(2, 2, z2) COLCORR(1, 3, z3) COLCORR(2, 3, z3)
        if (p == 0)       { CORNER(0,2,2,z2) CORNER(0,1,3,z3) CORNER(0,2,3,z3)
                            CORNER(1,2,2,z2) CORNER(1,1,3,z3) CORNER(1,2,3,z3) }
        else if (p == 1)  { CORNER(0,2,2,z2) CORNER(0,1,3,z3) CORNER(0,2,3,z3) }
        else if (p == 62) { CORNER(2,2,2,z2) CORNER(2,1,3,z3) CORNER(2,2,3,z3) }
        else if (p == 63) { CORNER(1,2,2,z2) CORNER(1,1,3,z3) CORNER(1,2,3,z3)
                            CORNER(2,2,2,z2) CORNER(2,1,3,z3) CORNER(2,2,3,z3) }
      }
      *reinterpret_cast<float4*>(&S[cs][((k & 15) << 6) + q0]) =
          make_float4(z0, z1, z2, z3);
    }
    // ---- drain-free barrier: LDS visibility only; stores stay in flight ----
    asm volatile("s_waitcnt lgkmcnt(0)" ::: "memory");
    __builtin_amdgcn_s_barrier();
    // ---- dump: wave w -> planes w and w+4, NT stores ----
    {
      int co_a = (cg << 3) + wave;
      float* dstA = outb + (((size_t)co_a) << 12) + ((r0 + (h << 4)) << 6);
      float* dstB = outb + (((size_t)(co_a + 4)) << 12) + ((r0 + (h << 4)) << 6);
      const floatx4* SpA = reinterpret_cast<const floatx4*>(&S[wave][0]);
      const floatx4* SpB = reinterpret_cast<const floatx4*>(&S[wave + 4][0]);
#pragma unroll
      for (int i = 0; i < 4; ++i) {
        int f4 = (i << 6) + lane;
        int kk = f4 >> 4, q0 = (f4 & 15) << 2;
        unsigned bits = (unsigned)(Rm[(h << 4) + kk] >> q0) & 0xFu;
        floatx4 va = SpA[f4];
        floatx4 vb = SpB[f4];
        if (!(bits & 1u)) { va.x = 0.f; vb.x = 0.f; }
        if (!(bits & 2u)) { va.y = 0.f; vb.y = 0.f; }
        if (!(bits & 4u)) { va.z = 0.f; vb.z = 0.f; }
        if (!(bits & 8u)) { va.w = 0.f; vb.w = 0.f; }
        __builtin_nontemporal_store(va, reinterpret_cast<floatx4*>(dstA + (f4 << 2)));
        __builtin_nontemporal_store(vb, reinterpret_cast<floatx4*>(dstB + (f4 << 2)));
      }
    }
    asm volatile("s_waitcnt lgkmcnt(0)" ::: "memory");
    __builtin_amdgcn_s_barrier();
  }
}

extern "C" void kernel_launch(void* const* d_in, const int* in_sizes, int n_in,
                              void* d_out, int out_size, void* d_ws, size_t ws_size,
                              hipStream_t stream) {
  const float* x  = (const float*)d_in[0];
  const float* W1 = (const float*)d_in[1];
  const float* b1 = (const float*)d_in[2];
  const float* W2 = (const float*)d_in[3];
  const float* b2 = (const float*)d_in[4];
  float* out = (float*)d_out;
  float* ws  = (float*)d_ws;
  int B = in_sizes[0] / 4096;  // 1024 images of 64x64x1

  hipLaunchKernelGGL(prep_kernel, dim3(26), dim3(BDIM), 0, stream, W1, b1, W2, b2, ws);
  hipLaunchKernelGGL(main_kernel, dim3(2 * B), dim3(BDIM), 0, stream, x, ws, out);
}